// Round 3
// baseline (61.745 us; speedup 1.0000x reference)
//
#include <hip/hip_runtime.h>
#include <hip/hip_cooperative_groups.h>

namespace cg = cooperative_groups;

// Problem constants
#define NB 4      // B
#define CA 128    // audio channels
#define CV 512    // video channels
#define NHH 8     // heads
#define TA 64     // audio time
#define FF 64     // audio freq
#define TV 256    // video time
#define REPC 4    // Cv/Ca
#define EPSV 1e-5f

// ws layout (floats): partials ws[q*512 + b*128 + ca], q = 0..7
//   q 0..3 audio (p1 sum, p1 sumsq, p2 sum, p2 sumsq)
//   q 4..7 video (f1 sum, f1 sumsq, f2 sum, f2 sumsq)

__device__ __forceinline__ float waveReduceSum(float x) {
  #pragma unroll
  for (int off = 32; off; off >>= 1) x += __shfl_xor(x, off);
  return x;
}
__device__ __forceinline__ float waveReduceMax(float x) {
  #pragma unroll
  for (int off = 32; off; off >>= 1) x = fmaxf(x, __shfl_xor(x, off));
  return x;
}
__device__ __forceinline__ float group16ReduceSum(float x) {
  #pragma unroll
  for (int off = 8; off; off >>= 1) x += __shfl_xor(x, off);
  return x;
}

// One block per (b, ca). 256 threads = 4 waves. Cooperative grid sync between
// the stats phase and the output phase.
__global__ __launch_bounds__(256, 2) void fused_kernel(
    const float* __restrict__ audio, const float* __restrict__ video,
    const float* __restrict__ p1_w, const float* __restrict__ p1_b,
    const float* __restrict__ p1_g, const float* __restrict__ p1_be,
    const float* __restrict__ p2_w, const float* __restrict__ p2_b,
    const float* __restrict__ p2_g, const float* __restrict__ p2_be,
    const float* __restrict__ f1_w, const float* __restrict__ f1_b,
    const float* __restrict__ f1_g,
    const float* __restrict__ f2_w, const float* __restrict__ f2_b,
    const float* __restrict__ f2_g, const float* __restrict__ f2_be,
    float* __restrict__ ws, float* __restrict__ out)
{
  const int bid = blockIdx.x;
  const int b = bid >> 7;              // / CA
  const int ca = bid & (CA - 1);
  const int c0 = ca * 4;
  const int tid = threadIdx.x;
  const int wv = tid >> 6, ln = tid & 63;

  __shared__ float red1[4], red2[4], fold[4][4], acc8[8];
  __shared__ float ssa[TA];        // raw row sums  sum_f audio[b,ca,ta,:]
  __shared__ float sg[4][TA];      // per-channel   sum_f relu(gate)

  const float4* ap4 = (const float4*)(audio + (size_t)(b * CA + ca) * (TA * FF));

  // ================= phase 1: stats partials =================
  {
    // audio slab (b,ca): S = sum, Q = sumsq over 4096 elements
    float s = 0.f, q = 0.f;
    #pragma unroll
    for (int i = 0; i < 4; ++i) {
      float4 v = ap4[tid + i * 256];
      s += v.x + v.y + v.z + v.w;
      q += v.x * v.x + v.y * v.y + v.z * v.z + v.w * v.w;
    }
    s = waveReduceSum(s); q = waveReduceSum(q);
    if (ln == 0) { red1[wv] = s; red2[wv] = q; }

    // video: wave wv handles channel c0+wv (256 floats, float4/lane)
    const int c = c0 + wv;
    const float4* vp4 = (const float4*)(video + (size_t)(b * CV + c) * TV);
    float4 v = vp4[ln];
    float vs = v.x + v.y + v.z + v.w;
    float vq = v.x * v.x + v.y * v.y + v.z * v.z + v.w * v.w;
    vs = waveReduceSum(vs); vq = waveReduceSum(vq);
    if (ln == 0) {
      float Wf = 0, Wfq = 0, Wfb = 0, Cf = 0, Cfq = 0;
      #pragma unroll
      for (int h = 0; h < NHH; ++h) {
        int j = c * NHH + h;
        float fw = f1_w[j], fb = f1_b[j];
        Wf += fw; Wfq += fw * fw; Wfb += fw * fb; Cf += fb; Cfq += fb * fb;
      }
      const float NT = (float)TV;
      float w2 = f2_w[c], b2 = f2_b[c];
      fold[wv][0] = Wf * vs + NT * Cf;
      fold[wv][1] = Wfq * vq + 2.f * Wfb * vs + NT * Cfq;
      fold[wv][2] = w2 * vs + NT * b2;
      fold[wv][3] = w2 * w2 * vq + 2.f * w2 * b2 * vs + NT * b2 * b2;
    }
    __syncthreads();
    if (tid == 0) {
      float S = red1[0] + red1[1] + red1[2] + red1[3];
      float Q = red2[0] + red2[1] + red2[2] + red2[3];
      float W1 = 0, W1q = 0, W1pb = 0, C1 = 0, C1q = 0;
      float W2 = 0, W2q = 0, W2pb = 0, C2 = 0, C2q = 0;
      #pragma unroll
      for (int r = 0; r < REPC; ++r) {
        int c2 = c0 + r;
        float w = p1_w[c2], bb = p1_b[c2];
        W1 += w; W1q += w * w; W1pb += w * bb; C1 += bb; C1q += bb * bb;
        float w2 = p2_w[c2], b2 = p2_b[c2];
        W2 += w2; W2q += w2 * w2; W2pb += w2 * b2; C2 += b2; C2q += b2 * b2;
      }
      const float NE = (float)(TA * FF);
      const int base = b * 128 + ca;
      ws[0 * 512 + base] = W1 * S + NE * C1;
      ws[1 * 512 + base] = W1q * Q + 2.f * W1pb * S + NE * C1q;
      ws[2 * 512 + base] = W2 * S + NE * C2;
      ws[3 * 512 + base] = W2q * Q + 2.f * W2pb * S + NE * C2q;
    }
    if (tid >= 4 && tid < 8) {
      int k = tid - 4;
      float p = fold[0][k] + fold[1][k] + fold[2][k] + fold[3][k];
      ws[(4 + k) * 512 + b * 128 + ca];   // address compute only (see store below)
      ws[(4 + k) * 512 + b * 128 + ca] = p;
    }
  }

  cg::this_grid().sync();

  // ================= phase 2: finalize (per block, L2-resident) =================
  {
    #pragma unroll
    for (int r = 0; r < 2; ++r) {
      int qq = wv * 2 + r;
      const float* p = ws + qq * 512 + b * 128;
      float s = p[ln] + p[64 + ln];
      s = waveReduceSum(s);
      if (ln == 0) acc8[qq] = s;
    }
  }
  __syncthreads();

  const float invNa = 1.f / (float)(CV * TA * FF);
  const float invN3 = 1.f / (float)(CV * NHH * TV);
  const float invN4 = 1.f / (float)(CV * TV);
  float mu1 = acc8[0] * invNa;
  float rs1 = rsqrtf(fmaxf(acc8[1] * invNa - mu1 * mu1, 0.f) + EPSV);
  float mu2 = acc8[2] * invNa;
  float rs2 = rsqrtf(fmaxf(acc8[3] * invNa - mu2 * mu2, 0.f) + EPSV);
  float mu3 = acc8[4] * invN3;
  float rs3 = rsqrtf(fmaxf(acc8[5] * invN3 - mu3 * mu3, 0.f) + EPSV);
  float mu4 = acc8[6] * invN4;
  float rs4 = rsqrtf(fmaxf(acc8[7] * invN4 - mu4 * mu4, 0.f) + EPSV);

  // ================= phase 3: output =================
  // gate affine consts for all 4 channels of this slab
  float A2a[4], B2a[4];
  #pragma unroll
  for (int cc = 0; cc < 4; ++cc) {
    int c = c0 + cc;
    A2a[cc] = p2_w[c] * rs2 * p2_g[c];
    B2a[cc] = (p2_b[c] - mu2) * rs2 * p2_g[c] + p2_be[c];
  }

  // audio pass 2: wave wv handles rows [wv*16, wv*16+16), 4 rows/iter
  #pragma unroll
  for (int i = 0; i < 4; ++i) {
    int rbase = wv * 16 + i * 4;
    float4 v = ap4[rbase * 16 + ln];   // lane ln: row rbase+(ln>>4), cols (ln&15)*4..+3
    float sa = v.x + v.y + v.z + v.w;
    float g0 = fmaxf(v.x * A2a[0] + B2a[0], 0.f) + fmaxf(v.y * A2a[0] + B2a[0], 0.f)
             + fmaxf(v.z * A2a[0] + B2a[0], 0.f) + fmaxf(v.w * A2a[0] + B2a[0], 0.f);
    float g1 = fmaxf(v.x * A2a[1] + B2a[1], 0.f) + fmaxf(v.y * A2a[1] + B2a[1], 0.f)
             + fmaxf(v.z * A2a[1] + B2a[1], 0.f) + fmaxf(v.w * A2a[1] + B2a[1], 0.f);
    float g2 = fmaxf(v.x * A2a[2] + B2a[2], 0.f) + fmaxf(v.y * A2a[2] + B2a[2], 0.f)
             + fmaxf(v.z * A2a[2] + B2a[2], 0.f) + fmaxf(v.w * A2a[2] + B2a[2], 0.f);
    float g3 = fmaxf(v.x * A2a[3] + B2a[3], 0.f) + fmaxf(v.y * A2a[3] + B2a[3], 0.f)
             + fmaxf(v.z * A2a[3] + B2a[3], 0.f) + fmaxf(v.w * A2a[3] + B2a[3], 0.f);
    sa = group16ReduceSum(sa);
    g0 = group16ReduceSum(g0);
    g1 = group16ReduceSum(g1);
    g2 = group16ReduceSum(g2);
    g3 = group16ReduceSum(g3);
    if ((ln & 15) == 0) {
      int rr = rbase + (ln >> 4);
      ssa[rr] = sa;
      sg[0][rr] = g0; sg[1][rr] = g1; sg[2][rr] = g2; sg[3][rr] = g3;
    }
  }

  // per-wave channel consts
  const int c = c0 + wv;
  const float A1 = p1_w[c] * rs1 * p1_g[c];
  const float B1 = (p1_b[c] - mu1) * rs1 * p1_g[c] + p1_be[c];
  float sw = 0.f;
  #pragma unroll
  for (int h = 0; h < NHH; ++h) sw += f1_w[c * NHH + h] * f1_g[c * NHH + h];
  const float alpha = rs3 * sw * (1.f / NHH);
  const float A4 = f2_w[c] * rs4 * f2_g[c];
  const float B4 = (f2_b[c] - mu4) * rs4 * f2_g[c] + f2_be[c];

  __syncthreads();

  // video: wave wv owns channel c; lane ln covers t = 4ln..4ln+3
  const float4* vp4 = (const float4*)(video + (size_t)(b * CV + c) * TV);
  float4 v = vp4[ln];
  float l0 = alpha * v.x, l1 = alpha * v.y, l2 = alpha * v.z, l3 = alpha * v.w;
  float m = waveReduceMax(fmaxf(fmaxf(l0, l1), fmaxf(l2, l3)));
  float e0 = __expf(l0 - m), e1 = __expf(l1 - m), e2 = __expf(l2 - m), e3 = __expf(l3 - m);
  float z = waveReduceSum(e0 + e1 + e2 + e3);
  float iz = 1.f / z;
  float sval = A1 * ssa[ln] + (float)FF * B1;   // a_val row-sum for row ln
  float sgate = sg[wv][ln];
  float4 o;
  o.x = e0 * iz * sval + (v.x * A4 + B4) * sgate + v.x;
  o.y = e1 * iz * sval + (v.y * A4 + B4) * sgate + v.y;
  o.z = e2 * iz * sval + (v.z * A4 + B4) * sgate + v.z;
  o.w = e3 * iz * sval + (v.w * A4 + B4) * sgate + v.w;
  ((float4*)(out + (size_t)(b * CV + c) * TV))[ln] = o;
}

extern "C" void kernel_launch(void* const* d_in, const int* in_sizes, int n_in,
                              void* d_out, int out_size, void* d_ws, size_t ws_size,
                              hipStream_t stream) {
  const float* audio = (const float*)d_in[0];
  const float* video = (const float*)d_in[1];
  const float* p1_w  = (const float*)d_in[2];
  const float* p1_b  = (const float*)d_in[3];
  const float* p1_g  = (const float*)d_in[4];
  const float* p1_be = (const float*)d_in[5];
  const float* p2_w  = (const float*)d_in[6];
  const float* p2_b  = (const float*)d_in[7];
  const float* p2_g  = (const float*)d_in[8];
  const float* p2_be = (const float*)d_in[9];
  const float* f1_w  = (const float*)d_in[10];
  const float* f1_b  = (const float*)d_in[11];
  const float* f1_g  = (const float*)d_in[12];
  const float* f2_w  = (const float*)d_in[14];
  const float* f2_b  = (const float*)d_in[15];
  const float* f2_g  = (const float*)d_in[16];
  const float* f2_be = (const float*)d_in[17];
  (void)in_sizes; (void)n_in; (void)out_size; (void)ws_size;

  float* ws  = (float*)d_ws;
  float* out = (float*)d_out;

  void* args[] = {
    (void*)&audio, (void*)&video,
    (void*)&p1_w, (void*)&p1_b, (void*)&p1_g, (void*)&p1_be,
    (void*)&p2_w, (void*)&p2_b, (void*)&p2_g, (void*)&p2_be,
    (void*)&f1_w, (void*)&f1_b, (void*)&f1_g,
    (void*)&f2_w, (void*)&f2_b, (void*)&f2_g, (void*)&f2_be,
    (void*)&ws, (void*)&out
  };
  hipLaunchCooperativeKernel((const void*)fused_kernel,
                             dim3(NB * CA), dim3(256), args, 0, stream);
}

// Round 4
// 15.297 us; speedup vs baseline: 4.0363x; 4.0363x over previous
//
#include <hip/hip_runtime.h>

// Problem constants
#define NB 4      // B
#define CA 128    // audio channels
#define CV 512    // video channels
#define NHH 8     // heads
#define TA 64     // audio time
#define FF 64     // audio freq
#define TV 256    // video time
#define REPC 4    // Cv/Ca
#define EPSV 1e-5f

// ws layout (floats): partials ws[q*512 + b*128 + ca], q = 0..7
//   q 0..3 audio (p1 sum, p1 sumsq, p2 sum, p2 sumsq)
//   q 4..7 video (f1 sum, f1 sumsq, f2 sum, f2 sumsq)

__device__ __forceinline__ float waveReduceSum(float x) {
  #pragma unroll
  for (int off = 32; off; off >>= 1) x += __shfl_xor(x, off);
  return x;
}
__device__ __forceinline__ float waveReduceMax(float x) {
  #pragma unroll
  for (int off = 32; off; off >>= 1) x = fmaxf(x, __shfl_xor(x, off));
  return x;
}
__device__ __forceinline__ float group16ReduceSum(float x) {
  #pragma unroll
  for (int off = 8; off; off >>= 1) x += __shfl_xor(x, off);
  return x;
}

__global__ __launch_bounds__(256) void stats_kernel(
    const float* __restrict__ audio, const float* __restrict__ video,
    const float* __restrict__ p1_w, const float* __restrict__ p1_b,
    const float* __restrict__ p2_w, const float* __restrict__ p2_b,
    const float* __restrict__ f1_w, const float* __restrict__ f1_b,
    const float* __restrict__ f2_w, const float* __restrict__ f2_b,
    float* __restrict__ ws)
{
  const int bid = blockIdx.x;
  const int tid = threadIdx.x;
  const int wv = tid >> 6, ln = tid & 63;
  __shared__ float red1[4], red2[4], fold[4][4];

  if (bid < NB * CA) {
    // ---- audio slab (b, ca): S = sum a, Q = sum a^2 over Ta*F (4096 elems) ----
    const int b = bid >> 7, ca = bid & (CA - 1);
    const float4* ap4 = (const float4*)(audio + (size_t)(b * CA + ca) * (TA * FF));
    float s = 0.f, q = 0.f;
    #pragma unroll
    for (int i = 0; i < 4; ++i) {
      float4 v = ap4[tid + i * 256];
      s += v.x + v.y + v.z + v.w;
      q += v.x * v.x + v.y * v.y + v.z * v.z + v.w * v.w;
    }
    s = waveReduceSum(s); q = waveReduceSum(q);
    if (ln == 0) { red1[wv] = s; red2[wv] = q; }
    __syncthreads();
    if (tid == 0) {
      float S = red1[0] + red1[1] + red1[2] + red1[3];
      float Q = red2[0] + red2[1] + red2[2] + red2[3];
      float W1 = 0, W1q = 0, W1pb = 0, C1 = 0, C1q = 0;
      float W2 = 0, W2q = 0, W2pb = 0, C2 = 0, C2q = 0;
      #pragma unroll
      for (int r = 0; r < REPC; ++r) {
        int c = ca * REPC + r;
        float w = p1_w[c], bb = p1_b[c];
        W1 += w; W1q += w * w; W1pb += w * bb; C1 += bb; C1q += bb * bb;
        float w2 = p2_w[c], b2 = p2_b[c];
        W2 += w2; W2q += w2 * w2; W2pb += w2 * b2; C2 += b2; C2q += b2 * b2;
      }
      const float NE = (float)(TA * FF);
      const int base = b * 128 + ca;
      ws[0 * 512 + base] = W1 * S + NE * C1;
      ws[1 * 512 + base] = W1q * Q + 2.f * W1pb * S + NE * C1q;
      ws[2 * 512 + base] = W2 * S + NE * C2;
      ws[3 * 512 + base] = W2q * Q + 2.f * W2pb * S + NE * C2q;
    }
  } else {
    // ---- video: 4 channels per block (wave wv -> channel), float4/lane ----
    const int vb = bid - NB * CA;
    const int b = vb >> 7, vi = vb & 127;
    const int c = vi * 4 + wv;
    const float4* vp4 = (const float4*)(video + (size_t)(b * CV + c) * TV);
    float4 v = vp4[ln];
    float s = v.x + v.y + v.z + v.w;
    float q = v.x * v.x + v.y * v.y + v.z * v.z + v.w * v.w;
    s = waveReduceSum(s); q = waveReduceSum(q);
    if (ln == 0) {
      float Wf = 0, Wfq = 0, Wfb = 0, Cf = 0, Cfq = 0;
      #pragma unroll
      for (int h = 0; h < NHH; ++h) {
        int j = c * NHH + h;
        float fw = f1_w[j], fb = f1_b[j];
        Wf += fw; Wfq += fw * fw; Wfb += fw * fb; Cf += fb; Cfq += fb * fb;
      }
      const float NT = (float)TV;
      float w2 = f2_w[c], b2 = f2_b[c];
      fold[wv][0] = Wf * s + NT * Cf;
      fold[wv][1] = Wfq * q + 2.f * Wfb * s + NT * Cfq;
      fold[wv][2] = w2 * s + NT * b2;
      fold[wv][3] = w2 * w2 * q + 2.f * w2 * b2 * s + NT * b2 * b2;
    }
    __syncthreads();
    if (tid < 4) {
      float p = fold[0][tid] + fold[1][tid] + fold[2][tid] + fold[3][tid];
      ws[(4 + tid) * 512 + b * 128 + vi] = p;
    }
  }
}

// One block per (b, ca): redundant finalize (L2-resident partials) + output.
__global__ __launch_bounds__(256) void out_kernel(
    const float* __restrict__ audio, const float* __restrict__ video,
    const float* __restrict__ p1_w, const float* __restrict__ p1_b,
    const float* __restrict__ p1_g, const float* __restrict__ p1_be,
    const float* __restrict__ p2_w, const float* __restrict__ p2_b,
    const float* __restrict__ p2_g, const float* __restrict__ p2_be,
    const float* __restrict__ f1_w, const float* __restrict__ f1_g,
    const float* __restrict__ f2_w, const float* __restrict__ f2_b,
    const float* __restrict__ f2_g, const float* __restrict__ f2_be,
    const float* __restrict__ ws, float* __restrict__ out)
{
  const int bid = blockIdx.x;
  const int b = bid >> 7;              // / CA
  const int ca = bid & (CA - 1);
  const int c0 = ca * 4;
  const int tid = threadIdx.x;
  const int wv = tid >> 6, ln = tid & 63;

  __shared__ float acc8[8];
  __shared__ float ssa[TA];        // raw row sums  sum_f audio[b,ca,ta,:]
  __shared__ float sg[4][TA];      // per-channel   sum_f relu(gate)

  // ---- redundant finalize: reduce 128 partials for each of this batch's 8 accs ----
  #pragma unroll
  for (int r = 0; r < 2; ++r) {
    int qq = wv * 2 + r;
    const float* p = ws + qq * 512 + b * 128;
    float s = p[ln] + p[64 + ln];
    s = waveReduceSum(s);
    if (ln == 0) acc8[qq] = s;
  }
  __syncthreads();

  const float invNa = 1.f / (float)(CV * TA * FF);
  const float invN3 = 1.f / (float)(CV * NHH * TV);
  const float invN4 = 1.f / (float)(CV * TV);
  float mu1 = acc8[0] * invNa;
  float rs1 = rsqrtf(fmaxf(acc8[1] * invNa - mu1 * mu1, 0.f) + EPSV);
  float mu2 = acc8[2] * invNa;
  float rs2 = rsqrtf(fmaxf(acc8[3] * invNa - mu2 * mu2, 0.f) + EPSV);
  float mu3 = acc8[4] * invN3;
  float rs3 = rsqrtf(fmaxf(acc8[5] * invN3 - mu3 * mu3, 0.f) + EPSV);
  float mu4 = acc8[6] * invN4;
  float rs4 = rsqrtf(fmaxf(acc8[7] * invN4 - mu4 * mu4, 0.f) + EPSV);

  // gate affine consts for all 4 channels of this slab (static-indexed regs)
  float A2a[4], B2a[4];
  #pragma unroll
  for (int cc = 0; cc < 4; ++cc) {
    int c = c0 + cc;
    A2a[cc] = p2_w[c] * rs2 * p2_g[c];
    B2a[cc] = (p2_b[c] - mu2) * rs2 * p2_g[c] + p2_be[c];
  }

  // ---- audio phase: wave wv handles rows [wv*16, wv*16+16), 4 rows/iter ----
  const float4* ap4 = (const float4*)(audio + (size_t)(b * CA + ca) * (TA * FF));
  #pragma unroll
  for (int i = 0; i < 4; ++i) {
    int rbase = wv * 16 + i * 4;
    float4 v = ap4[rbase * 16 + ln];   // lane ln: row rbase+(ln>>4), cols (ln&15)*4..+3
    float sa = v.x + v.y + v.z + v.w;
    float g0 = fmaxf(v.x * A2a[0] + B2a[0], 0.f) + fmaxf(v.y * A2a[0] + B2a[0], 0.f)
             + fmaxf(v.z * A2a[0] + B2a[0], 0.f) + fmaxf(v.w * A2a[0] + B2a[0], 0.f);
    float g1 = fmaxf(v.x * A2a[1] + B2a[1], 0.f) + fmaxf(v.y * A2a[1] + B2a[1], 0.f)
             + fmaxf(v.z * A2a[1] + B2a[1], 0.f) + fmaxf(v.w * A2a[1] + B2a[1], 0.f);
    float g2 = fmaxf(v.x * A2a[2] + B2a[2], 0.f) + fmaxf(v.y * A2a[2] + B2a[2], 0.f)
             + fmaxf(v.z * A2a[2] + B2a[2], 0.f) + fmaxf(v.w * A2a[2] + B2a[2], 0.f);
    float g3 = fmaxf(v.x * A2a[3] + B2a[3], 0.f) + fmaxf(v.y * A2a[3] + B2a[3], 0.f)
             + fmaxf(v.z * A2a[3] + B2a[3], 0.f) + fmaxf(v.w * A2a[3] + B2a[3], 0.f);
    sa = group16ReduceSum(sa);
    g0 = group16ReduceSum(g0);
    g1 = group16ReduceSum(g1);
    g2 = group16ReduceSum(g2);
    g3 = group16ReduceSum(g3);
    if ((ln & 15) == 0) {
      int rr = rbase + (ln >> 4);
      ssa[rr] = sa;
      sg[0][rr] = g0; sg[1][rr] = g1; sg[2][rr] = g2; sg[3][rr] = g3;
    }
  }

  // ---- per-wave channel consts ----
  const int c = c0 + wv;
  const float A1 = p1_w[c] * rs1 * p1_g[c];
  const float B1 = (p1_b[c] - mu1) * rs1 * p1_g[c] + p1_be[c];
  float sw = 0.f;
  #pragma unroll
  for (int h = 0; h < NHH; ++h) sw += f1_w[c * NHH + h] * f1_g[c * NHH + h];
  const float alpha = rs3 * sw * (1.f / NHH);
  const float A4 = f2_w[c] * rs4 * f2_g[c];
  const float B4 = (f2_b[c] - mu4) * rs4 * f2_g[c] + f2_be[c];

  __syncthreads();

  // ---- video phase: wave wv owns channel c; lane ln covers t = 4ln..4ln+3 ----
  const float4* vp4 = (const float4*)(video + (size_t)(b * CV + c) * TV);
  float4 v = vp4[ln];
  float l0 = alpha * v.x, l1 = alpha * v.y, l2 = alpha * v.z, l3 = alpha * v.w;
  float m = waveReduceMax(fmaxf(fmaxf(l0, l1), fmaxf(l2, l3)));
  float e0 = __expf(l0 - m), e1 = __expf(l1 - m), e2 = __expf(l2 - m), e3 = __expf(l3 - m);
  float z = waveReduceSum(e0 + e1 + e2 + e3);
  float iz = 1.f / z;
  float sval = A1 * ssa[ln] + (float)FF * B1;   // a_val row-sum for row ln
  float sgate = sg[wv][ln];
  float4 o;
  o.x = e0 * iz * sval + (v.x * A4 + B4) * sgate + v.x;
  o.y = e1 * iz * sval + (v.y * A4 + B4) * sgate + v.y;
  o.z = e2 * iz * sval + (v.z * A4 + B4) * sgate + v.z;
  o.w = e3 * iz * sval + (v.w * A4 + B4) * sgate + v.w;
  ((float4*)(out + (size_t)(b * CV + c) * TV))[ln] = o;
}

extern "C" void kernel_launch(void* const* d_in, const int* in_sizes, int n_in,
                              void* d_out, int out_size, void* d_ws, size_t ws_size,
                              hipStream_t stream) {
  const float* audio = (const float*)d_in[0];
  const float* video = (const float*)d_in[1];
  const float* p1_w  = (const float*)d_in[2];
  const float* p1_b  = (const float*)d_in[3];
  const float* p1_g  = (const float*)d_in[4];
  const float* p1_be = (const float*)d_in[5];
  const float* p2_w  = (const float*)d_in[6];
  const float* p2_b  = (const float*)d_in[7];
  const float* p2_g  = (const float*)d_in[8];
  const float* p2_be = (const float*)d_in[9];
  const float* f1_w  = (const float*)d_in[10];
  const float* f1_b  = (const float*)d_in[11];
  const float* f1_g  = (const float*)d_in[12];
  const float* f2_w  = (const float*)d_in[14];
  const float* f2_b  = (const float*)d_in[15];
  const float* f2_g  = (const float*)d_in[16];
  const float* f2_be = (const float*)d_in[17];
  (void)in_sizes; (void)n_in; (void)out_size; (void)ws_size;

  float* ws  = (float*)d_ws;
  float* out = (float*)d_out;

  stats_kernel<<<NB * CA + NB * CV / 4, 256, 0, stream>>>(
      audio, video, p1_w, p1_b, p2_w, p2_b, f1_w, f1_b, f2_w, f2_b, ws);

  out_kernel<<<NB * CA, 256, 0, stream>>>(
      audio, video,
      p1_w, p1_b, p1_g, p1_be,
      p2_w, p2_b, p2_g, p2_be,
      f1_w, f1_g, f2_w, f2_b, f2_g, f2_be,
      ws, out);
}

// Round 5
// 14.333 us; speedup vs baseline: 4.3079x; 1.0673x over previous
//
#include <hip/hip_runtime.h>

// Problem constants
#define NB 4      // B
#define CA 128    // audio channels
#define CV 512    // video channels
#define NHH 8     // heads
#define TA 64     // audio time
#define FF 64     // audio freq
#define TV 256    // video time
#define REPC 4    // Cv/Ca
#define EPSV 1e-5f

// ws layout (floats): partials ws[q*512 + b*128 + ca], q = 0..7
//   q 0..3 audio (p1 sum, p1 sumsq, p2 sum, p2 sumsq)
//   q 4..7 video (f1 sum, f1 sumsq, f2 sum, f2 sumsq)

__device__ __forceinline__ float waveReduceSum(float x) {
  #pragma unroll
  for (int off = 32; off; off >>= 1) x += __shfl_xor(x, off);
  return x;
}
__device__ __forceinline__ float waveReduceMax(float x) {
  #pragma unroll
  for (int off = 32; off; off >>= 1) x = fmaxf(x, __shfl_xor(x, off));
  return x;
}
__device__ __forceinline__ float group4ReduceSum(float x) {
  x += __shfl_xor(x, 1);
  x += __shfl_xor(x, 2);
  return x;
}

// One block per (b, ca): audio slab stats + 4 video channels (wave wv -> c0+wv).
__global__ __launch_bounds__(256) void stats_kernel(
    const float* __restrict__ audio, const float* __restrict__ video,
    const float* __restrict__ p1_w, const float* __restrict__ p1_b,
    const float* __restrict__ p2_w, const float* __restrict__ p2_b,
    const float* __restrict__ f1_w, const float* __restrict__ f1_b,
    const float* __restrict__ f2_w, const float* __restrict__ f2_b,
    float* __restrict__ ws)
{
  const int bid = blockIdx.x;
  const int b = bid >> 7, ca = bid & (CA - 1);
  const int c0 = ca * 4;
  const int tid = threadIdx.x;
  const int wv = tid >> 6, ln = tid & 63;
  const int c = c0 + wv;
  __shared__ float red1[4], red2[4], fold[4][4];

  // ---- issue all payload loads up front (5 independent float4 per thread) ----
  const float4* ap4 = (const float4*)(audio + (size_t)(b * CA + ca) * (TA * FF));
  float4 a0 = ap4[tid];
  float4 a1 = ap4[tid + 256];
  float4 a2 = ap4[tid + 512];
  float4 a3 = ap4[tid + 768];
  const float4* vp4 = (const float4*)(video + (size_t)(b * CV + c) * TV);
  float4 v = vp4[ln];

  // ---- audio slab: S = sum, Q = sumsq over 4096 elements ----
  float s = a0.x + a0.y + a0.z + a0.w + a1.x + a1.y + a1.z + a1.w
          + a2.x + a2.y + a2.z + a2.w + a3.x + a3.y + a3.z + a3.w;
  float q = a0.x * a0.x + a0.y * a0.y + a0.z * a0.z + a0.w * a0.w
          + a1.x * a1.x + a1.y * a1.y + a1.z * a1.z + a1.w * a1.w
          + a2.x * a2.x + a2.y * a2.y + a2.z * a2.z + a2.w * a2.w
          + a3.x * a3.x + a3.y * a3.y + a3.z * a3.z + a3.w * a3.w;
  s = waveReduceSum(s); q = waveReduceSum(q);
  if (ln == 0) { red1[wv] = s; red2[wv] = q; }

  // ---- video channel c: per-wave sum/sumsq + folded partials ----
  float vs = v.x + v.y + v.z + v.w;
  float vq = v.x * v.x + v.y * v.y + v.z * v.z + v.w * v.w;
  vs = waveReduceSum(vs); vq = waveReduceSum(vq);
  if (ln == 0) {
    float Wf = 0, Wfq = 0, Wfb = 0, Cf = 0, Cfq = 0;
    #pragma unroll
    for (int h = 0; h < NHH; ++h) {
      int j = c * NHH + h;
      float fw = f1_w[j], fb = f1_b[j];
      Wf += fw; Wfq += fw * fw; Wfb += fw * fb; Cf += fb; Cfq += fb * fb;
    }
    const float NT = (float)TV;
    float w2 = f2_w[c], b2 = f2_b[c];
    fold[wv][0] = Wf * vs + NT * Cf;
    fold[wv][1] = Wfq * vq + 2.f * Wfb * vs + NT * Cfq;
    fold[wv][2] = w2 * vs + NT * b2;
    fold[wv][3] = w2 * w2 * vq + 2.f * w2 * b2 * vs + NT * b2 * b2;
  }
  __syncthreads();
  if (tid == 0) {
    float S = red1[0] + red1[1] + red1[2] + red1[3];
    float Q = red2[0] + red2[1] + red2[2] + red2[3];
    float W1 = 0, W1q = 0, W1pb = 0, C1 = 0, C1q = 0;
    float W2 = 0, W2q = 0, W2pb = 0, C2 = 0, C2q = 0;
    #pragma unroll
    for (int r = 0; r < REPC; ++r) {
      int c2 = c0 + r;
      float w = p1_w[c2], bb = p1_b[c2];
      W1 += w; W1q += w * w; W1pb += w * bb; C1 += bb; C1q += bb * bb;
      float w2 = p2_w[c2], b2 = p2_b[c2];
      W2 += w2; W2q += w2 * w2; W2pb += w2 * b2; C2 += b2; C2q += b2 * b2;
    }
    const float NE = (float)(TA * FF);
    const int base = b * 128 + ca;
    ws[0 * 512 + base] = W1 * S + NE * C1;
    ws[1 * 512 + base] = W1q * Q + 2.f * W1pb * S + NE * C1q;
    ws[2 * 512 + base] = W2 * S + NE * C2;
    ws[3 * 512 + base] = W2q * Q + 2.f * W2pb * S + NE * C2q;
  }
  if (tid >= 4 && tid < 8) {
    int k = tid - 4;
    float p = fold[0][k] + fold[1][k] + fold[2][k] + fold[3][k];
    ws[(4 + k) * 512 + b * 128 + ca] = p;
  }
}

// One block per (b, ca): prefetch payload, redundant finalize, fused output.
__global__ __launch_bounds__(256) void out_kernel(
    const float* __restrict__ audio, const float* __restrict__ video,
    const float* __restrict__ p1_w, const float* __restrict__ p1_b,
    const float* __restrict__ p1_g, const float* __restrict__ p1_be,
    const float* __restrict__ p2_w, const float* __restrict__ p2_b,
    const float* __restrict__ p2_g, const float* __restrict__ p2_be,
    const float* __restrict__ f1_w, const float* __restrict__ f1_g,
    const float* __restrict__ f2_w, const float* __restrict__ f2_b,
    const float* __restrict__ f2_g, const float* __restrict__ f2_be,
    const float* __restrict__ ws, float* __restrict__ out)
{
  const int bid = blockIdx.x;
  const int b = bid >> 7;              // / CA
  const int ca = bid & (CA - 1);
  const int c0 = ca * 4;
  const int tid = threadIdx.x;
  const int wv = tid >> 6, ln = tid & 63;
  const int c = c0 + wv;
  const int row = wv * 16 + (ln >> 2);   // audio row handled by this lane's group
  const int lq = ln & 3;                 // position within 4-lane group

  __shared__ float acc8[8];
  __shared__ float ssa[TA];        // raw row sums  sum_f audio[b,ca,ta,:]
  __shared__ float sg[4][TA];      // per-channel   sum_f relu(gate)

  // ================= prefetch all payload (independent of finalize) ==========
  const float4* ap4 = (const float4*)(audio + (size_t)(b * CA + ca) * (TA * FF));
  const int abase = row * 16 + lq;
  float4 av0 = ap4[abase];
  float4 av1 = ap4[abase + 4];
  float4 av2 = ap4[abase + 8];
  float4 av3 = ap4[abase + 12];
  const float4* vp4 = (const float4*)(video + (size_t)(b * CV + c) * TV);
  float4 v = vp4[ln];
  // per-slab gate params (vector loads; c0 = 4*ca so float4-aligned)
  float4 p2w4  = ((const float4*)p2_w)[ca];
  float4 p2b4  = ((const float4*)p2_b)[ca];
  float4 p2g4  = ((const float4*)p2_g)[ca];
  float4 p2be4 = ((const float4*)p2_be)[ca];
  // per-wave channel params
  float p1wv = p1_w[c], p1bv = p1_b[c], p1gv = p1_g[c], p1bev = p1_be[c];
  float4 f1wa = ((const float4*)f1_w)[c * 2], f1wb = ((const float4*)f1_w)[c * 2 + 1];
  float4 f1ga = ((const float4*)f1_g)[c * 2], f1gb = ((const float4*)f1_g)[c * 2 + 1];
  float f2wv = f2_w[c], f2bv = f2_b[c], f2gv = f2_g[c], f2bev = f2_be[c];

  // ================= redundant finalize (runs while loads in flight) =========
  #pragma unroll
  for (int r = 0; r < 2; ++r) {
    int qq = wv * 2 + r;
    const float* p = ws + qq * 512 + b * 128;
    float s = p[ln] + p[64 + ln];
    s = waveReduceSum(s);
    if (ln == 0) acc8[qq] = s;
  }
  __syncthreads();

  const float invNa = 1.f / (float)(CV * TA * FF);
  const float invN3 = 1.f / (float)(CV * NHH * TV);
  const float invN4 = 1.f / (float)(CV * TV);
  float mu1 = acc8[0] * invNa;
  float rs1 = rsqrtf(fmaxf(acc8[1] * invNa - mu1 * mu1, 0.f) + EPSV);
  float mu2 = acc8[2] * invNa;
  float rs2 = rsqrtf(fmaxf(acc8[3] * invNa - mu2 * mu2, 0.f) + EPSV);
  float mu3 = acc8[4] * invN3;
  float rs3 = rsqrtf(fmaxf(acc8[5] * invN3 - mu3 * mu3, 0.f) + EPSV);
  float mu4 = acc8[6] * invN4;
  float rs4 = rsqrtf(fmaxf(acc8[7] * invN4 - mu4 * mu4, 0.f) + EPSV);

  // gate affine consts for the slab's 4 channels
  float A2a[4], B2a[4];
  A2a[0] = p2w4.x * rs2 * p2g4.x;  B2a[0] = (p2b4.x - mu2) * rs2 * p2g4.x + p2be4.x;
  A2a[1] = p2w4.y * rs2 * p2g4.y;  B2a[1] = (p2b4.y - mu2) * rs2 * p2g4.y + p2be4.y;
  A2a[2] = p2w4.z * rs2 * p2g4.z;  B2a[2] = (p2b4.z - mu2) * rs2 * p2g4.z + p2be4.z;
  A2a[3] = p2w4.w * rs2 * p2g4.w;  B2a[3] = (p2b4.w - mu2) * rs2 * p2g4.w + p2be4.w;

  // ---- audio: one pass, lane group of 4 per row, 2-round shuffle reduce ----
  float sa = av0.x + av0.y + av0.z + av0.w + av1.x + av1.y + av1.z + av1.w
           + av2.x + av2.y + av2.z + av2.w + av3.x + av3.y + av3.z + av3.w;
  float g[4];
  #pragma unroll
  for (int cc = 0; cc < 4; ++cc) {
    float A = A2a[cc], Bv = B2a[cc];
    g[cc] = fmaxf(av0.x * A + Bv, 0.f) + fmaxf(av0.y * A + Bv, 0.f)
          + fmaxf(av0.z * A + Bv, 0.f) + fmaxf(av0.w * A + Bv, 0.f)
          + fmaxf(av1.x * A + Bv, 0.f) + fmaxf(av1.y * A + Bv, 0.f)
          + fmaxf(av1.z * A + Bv, 0.f) + fmaxf(av1.w * A + Bv, 0.f)
          + fmaxf(av2.x * A + Bv, 0.f) + fmaxf(av2.y * A + Bv, 0.f)
          + fmaxf(av2.z * A + Bv, 0.f) + fmaxf(av2.w * A + Bv, 0.f)
          + fmaxf(av3.x * A + Bv, 0.f) + fmaxf(av3.y * A + Bv, 0.f)
          + fmaxf(av3.z * A + Bv, 0.f) + fmaxf(av3.w * A + Bv, 0.f);
  }
  sa = group4ReduceSum(sa);
  g[0] = group4ReduceSum(g[0]);
  g[1] = group4ReduceSum(g[1]);
  g[2] = group4ReduceSum(g[2]);
  g[3] = group4ReduceSum(g[3]);
  if (lq == 0) {
    ssa[row] = sa;
    sg[0][row] = g[0]; sg[1][row] = g[1]; sg[2][row] = g[2]; sg[3][row] = g[3];
  }

  // ---- per-wave channel consts ----
  const float A1 = p1wv * rs1 * p1gv;
  const float B1 = (p1bv - mu1) * rs1 * p1gv + p1bev;
  float sw = f1wa.x * f1ga.x + f1wa.y * f1ga.y + f1wa.z * f1ga.z + f1wa.w * f1ga.w
           + f1wb.x * f1gb.x + f1wb.y * f1gb.y + f1wb.z * f1gb.z + f1wb.w * f1gb.w;
  const float alpha = rs3 * sw * (1.f / NHH);
  const float A4 = f2wv * rs4 * f2gv;
  const float B4 = (f2bv - mu4) * rs4 * f2gv + f2bev;

  __syncthreads();

  // ---- video: wave wv owns channel c; lane ln covers t = 4ln..4ln+3 ----
  float l0 = alpha * v.x, l1 = alpha * v.y, l2 = alpha * v.z, l3 = alpha * v.w;
  float m = waveReduceMax(fmaxf(fmaxf(l0, l1), fmaxf(l2, l3)));
  float e0 = __expf(l0 - m), e1 = __expf(l1 - m), e2 = __expf(l2 - m), e3 = __expf(l3 - m);
  float z = waveReduceSum(e0 + e1 + e2 + e3);
  float iz = 1.f / z;
  float sval = A1 * ssa[ln] + (float)FF * B1;   // a_val row-sum for row ln
  float sgate = sg[wv][ln];
  float4 o;
  o.x = e0 * iz * sval + (v.x * A4 + B4) * sgate + v.x;
  o.y = e1 * iz * sval + (v.y * A4 + B4) * sgate + v.y;
  o.z = e2 * iz * sval + (v.z * A4 + B4) * sgate + v.z;
  o.w = e3 * iz * sval + (v.w * A4 + B4) * sgate + v.w;
  ((float4*)(out + (size_t)(b * CV + c) * TV))[ln] = o;
}

extern "C" void kernel_launch(void* const* d_in, const int* in_sizes, int n_in,
                              void* d_out, int out_size, void* d_ws, size_t ws_size,
                              hipStream_t stream) {
  const float* audio = (const float*)d_in[0];
  const float* video = (const float*)d_in[1];
  const float* p1_w  = (const float*)d_in[2];
  const float* p1_b  = (const float*)d_in[3];
  const float* p1_g  = (const float*)d_in[4];
  const float* p1_be = (const float*)d_in[5];
  const float* p2_w  = (const float*)d_in[6];
  const float* p2_b  = (const float*)d_in[7];
  const float* p2_g  = (const float*)d_in[8];
  const float* p2_be = (const float*)d_in[9];
  const float* f1_w  = (const float*)d_in[10];
  const float* f1_b  = (const float*)d_in[11];
  const float* f1_g  = (const float*)d_in[12];
  const float* f2_w  = (const float*)d_in[14];
  const float* f2_b  = (const float*)d_in[15];
  const float* f2_g  = (const float*)d_in[16];
  const float* f2_be = (const float*)d_in[17];
  (void)in_sizes; (void)n_in; (void)out_size; (void)ws_size;

  float* ws  = (float*)d_ws;
  float* out = (float*)d_out;

  stats_kernel<<<NB * CA, 256, 0, stream>>>(
      audio, video, p1_w, p1_b, p2_w, p2_b, f1_w, f1_b, f2_w, f2_b, ws);

  out_kernel<<<NB * CA, 256, 0, stream>>>(
      audio, video,
      p1_w, p1_b, p1_g, p1_be,
      p2_w, p2_b, p2_g, p2_be,
      f1_w, f1_g, f2_w, f2_b, f2_g, f2_be,
      ws, out);
}